// Round 13
// baseline (1107.637 us; speedup 1.0000x reference)
//
#include <hip/hip_runtime.h>
#include <hip/hip_bf16.h>

// BitNet FFN: LN -> act_quant/ternary-W matmul -> GELU(erf) -> act_quant/ternary-W matmul
// Shapes: x[4,4096,2048] f32, w1[8192,2048], w2[2048,8192], out [16384,2048] f32.
// R13: R10 verbatim (best: 311us GEMM2) except block geometry: 256 threads /
// 4 waves / 256x128 tile / 48KiB LDS -> TWO blocks (barrier domains) per CU.
// R5-R12 ran ONE 512-thread block/CU (224 regs/wave incl. AGPR acc => 2
// waves/SIMD), so all waves phase-locked and MFMA+LDS pipes alternated
// (serialized sum). Two desynced blocks overlap the pipes (m114).
// i8 MFMA 16x16x64; i32 accum exact -> output bit-identical (absmax 2.539e-2).
// Peak ws 177 MiB; d_out doubles as f32 GELU staging per M-chunk.

typedef __attribute__((ext_vector_type(4))) int int4v;

#define D_DIM 2048
#define H_DIM 8192
#define M_DIM 16384
#define MCHUNK 4096

// ---------- small helpers ----------
__device__ __forceinline__ float block_sum(float v, float* buf) {
#pragma unroll
  for (int o = 32; o > 0; o >>= 1) v += __shfl_down(v, o, 64);
  const int lane = threadIdx.x & 63, w = threadIdx.x >> 6;
  if (lane == 0) buf[w] = v;
  __syncthreads();
  float r = buf[0] + buf[1] + buf[2] + buf[3];
  __syncthreads();
  return r;
}
__device__ __forceinline__ float block_max(float v, float* buf) {
#pragma unroll
  for (int o = 32; o > 0; o >>= 1) v = fmaxf(v, __shfl_down(v, o, 64));
  const int lane = threadIdx.x & 63, w = threadIdx.x >> 6;
  if (lane == 0) buf[w] = v;
  __syncthreads();
  float r = fmaxf(fmaxf(buf[0], buf[1]), fmaxf(buf[2], buf[3]));
  __syncthreads();
  return r;
}

__device__ __forceinline__ void lds16(const signed char* g, signed char* l) {
  __builtin_amdgcn_global_load_lds(
      (const __attribute__((address_space(1))) unsigned int*)g,
      (__attribute__((address_space(3))) unsigned int*)l, 16, 0, 0);
}

// ---------- weight abs-mean (deterministic two-stage) ----------
__global__ __launch_bounds__(256) void absmean_partial(const float* __restrict__ w,
                                                       int n, double* __restrict__ part) {
  __shared__ float buf[4];
  float s = 0.0f;
  const long stride = (long)gridDim.x * 256 * 4;
  for (long i = ((long)blockIdx.x * 256 + threadIdx.x) * 4; i < n; i += stride) {
    float4 v = *(const float4*)(w + i);
    s += fabsf(v.x) + fabsf(v.y) + fabsf(v.z) + fabsf(v.w);
  }
  float r = block_sum(s, buf);
  if (threadIdx.x == 0) part[blockIdx.x] = (double)r;
}

__global__ __launch_bounds__(256) void absmean_final(const double* __restrict__ part,
                                                     int nb, double n, double* __restrict__ out) {
  __shared__ double buf[4];
  double s = 0.0;
  for (int i = threadIdx.x; i < nb; i += 256) s += part[i];
#pragma unroll
  for (int o = 32; o > 0; o >>= 1) s += __shfl_down(s, o, 64);
  const int lane = threadIdx.x & 63, w = threadIdx.x >> 6;
  if (lane == 0) buf[w] = s;
  __syncthreads();
  if (threadIdx.x == 0) out[0] = (buf[0] + buf[1] + buf[2] + buf[3]) / n;
}

// ---------- ternary weight quant -> i8 {-1,0,1} ----------
__global__ __launch_bounds__(256) void wquant_kernel(const float* __restrict__ w,
                                                     const double* __restrict__ mean,
                                                     signed char* __restrict__ wq, int n) {
  long i = ((long)blockIdx.x * 256 + threadIdx.x) * 4;
  if (i >= n) return;
  const float s = 1.0f / (float)fmax(mean[0], 1e-5);
  float4 v = *(const float4*)(w + i);
  __align__(4) signed char q[4];
  q[0] = (signed char)(int)fminf(fmaxf(rintf(v.x * s), -1.f), 1.f);
  q[1] = (signed char)(int)fminf(fmaxf(rintf(v.y * s), -1.f), 1.f);
  q[2] = (signed char)(int)fminf(fmaxf(rintf(v.z * s), -1.f), 1.f);
  q[3] = (signed char)(int)fminf(fmaxf(rintf(v.w * s), -1.f), 1.f);
  *(int*)(wq + i) = *(int*)q;
}

// ---------- fused LayerNorm + per-token int8 absmax quant -> i8 ----------
__global__ __launch_bounds__(256) void ln_quant_kernel(const float* __restrict__ x,
                                                       const float* __restrict__ gamma,
                                                       const float* __restrict__ beta,
                                                       signed char* __restrict__ aq,
                                                       float* __restrict__ ds) {
  __shared__ float buf[4];
  const int t = threadIdx.x;
  const long row = blockIdx.x;
  const float* xr = x + row * (long)D_DIM;
  float v[8];
  *(float4*)(v)     = *(const float4*)(xr + t * 8);
  *(float4*)(v + 4) = *(const float4*)(xr + t * 8 + 4);
  float s = 0.f;
#pragma unroll
  for (int i = 0; i < 8; ++i) s += v[i];
  s = block_sum(s, buf);
  const float mu = s * (1.0f / 2048.0f);
  float sq = 0.f;
#pragma unroll
  for (int i = 0; i < 8; ++i) { float d = v[i] - mu; sq += d * d; }
  sq = block_sum(sq, buf);
  const float inv = 1.0f / sqrtf(sq * (1.0f / 2048.0f) + 1e-5f);
  float gam[8], bet[8];
  *(float4*)(gam)     = *(const float4*)(gamma + t * 8);
  *(float4*)(gam + 4) = *(const float4*)(gamma + t * 8 + 4);
  *(float4*)(bet)     = *(const float4*)(beta + t * 8);
  *(float4*)(bet + 4) = *(const float4*)(beta + t * 8 + 4);
  float xn[8]; float am = 0.f;
#pragma unroll
  for (int i = 0; i < 8; ++i) {
    xn[i] = (v[i] - mu) * inv * gam[i] + bet[i];
    am = fmaxf(am, fabsf(xn[i]));
  }
  am = block_max(am, buf);
  am = fmaxf(am, 1e-5f);
  const float qs = 127.0f / am;
  __align__(8) signed char q[8];
#pragma unroll
  for (int i = 0; i < 8; ++i)
    q[i] = (signed char)(int)fminf(fmaxf(rintf(xn[i] * qs), -128.f), 127.f);
  *(long*)(aq + row * D_DIM + t * 8) = *(long*)q;
  if (t == 0) ds[row] = am / 127.0f;
}

// ---------- per-token re-quant from f32 h chunk -> dense i8 ----------
__global__ __launch_bounds__(256) void hquant32_kernel(const float* __restrict__ src,
                                                       signed char* __restrict__ dst,
                                                       float* __restrict__ ds2) {
  __shared__ float buf[4];
  const int t = threadIdx.x;
  const long row = blockIdx.x;
  const float* sr = src + row * (long)H_DIM;
  float v[4][8];
#pragma unroll
  for (int c = 0; c < 4; ++c) {
    *(float4*)(v[c])     = *(const float4*)(sr + (c * 256 + t) * 8);
    *(float4*)(v[c] + 4) = *(const float4*)(sr + (c * 256 + t) * 8 + 4);
  }
  float am = 0.f;
#pragma unroll
  for (int c = 0; c < 4; ++c)
#pragma unroll
    for (int i = 0; i < 8; ++i) am = fmaxf(am, fabsf(v[c][i]));
  am = block_max(am, buf);
  am = fmaxf(am, 1e-5f);
  const float qs = 127.0f / am;
  signed char* dr = dst + row * (long)H_DIM;
#pragma unroll
  for (int c = 0; c < 4; ++c) {
    __align__(8) signed char o[8];
#pragma unroll
    for (int i = 0; i < 8; ++i)
      o[i] = (signed char)(int)fminf(fmaxf(rintf(v[c][i] * qs), -128.f), 127.f);
    *(long*)(dr + (c * 256 + t) * 8) = *(long*)o;
  }
  if (t == 0) ds2[row] = am / 127.0f;
}

// ---------- subtile readers / MFMA quadrant (i8, K=64 per instr) ----------
__device__ __forceinline__ void read_a4(const signed char* sm, int base, int4v (&af)[4]) {
#pragma unroll
  for (int ms = 0; ms < 4; ++ms)
    af[ms] = *(const int4v*)&sm[base + ms * 1024];   // 16 rows * 64B
}
__device__ __forceinline__ void read_b2(const signed char* sm, int base, int4v (&bf)[2]) {
#pragma unroll
  for (int ns = 0; ns < 2; ++ns)
    bf[ns] = *(const int4v*)&sm[base + ns * 1024];
}
__device__ __forceinline__ void mfma_q(const int4v (&af)[4], const int4v (&bf)[2],
                                       int4v (&acc)[8][4], int m0, int n0) {
#pragma unroll
  for (int ms = 0; ms < 4; ++ms)
#pragma unroll
    for (int ns = 0; ns < 2; ++ns)
      acc[m0 + ms][n0 + ns] = __builtin_amdgcn_mfma_i32_16x16x64_i8(
          af[ms], bf[ns], acc[m0 + ms][n0 + ns], 0, 0, 0);
}

// ---------- 256x128 BK=64 8-phase i8 GEMM, A[M,K] x B[N,K]^T ----------
// 4 waves (2M x 2N), 256 threads; per-wave 128x64 output (identical to R10).
// LDS: A 2x16KB, B 2x8KB = 48KB -> 2 blocks/CU (2 independent barrier domains).
// Same chunk-XOR layout as R10: LDS[row][p] = global[row][p ^ (row&3)^((row>>2)&3)].
// Iteration = 2 K-tiles, 8 phases; per K-tile stage A-h0,A-h1,B (2 loads each);
// counted vmcnt(2) at P3/P7.
// EPI==1: dequant+bias+exact GELU -> f32.  EPI==2: dequant+bias -> f32.
template <int EPI>
__global__ __launch_bounds__(256, 2) void gemm256_kernel(
    const signed char* __restrict__ A,
    const signed char* __restrict__ Bm,
    const float* __restrict__ dsA,
    const double* __restrict__ meanw,
    const float* __restrict__ bias,
    float* __restrict__ outf,
    int NBX, int N, int K) {
  __shared__ __align__(16) signed char smA[2 * 256 * 64];   // 32KB
  __shared__ __align__(16) signed char smB[2 * 128 * 64];   // 16KB
  const int tid = threadIdx.x;
  const int lane = tid & 63;
  const int wv = tid >> 6;    // 0..3
  const int wr = wv >> 1;     // 0..1 (M half: 128 rows)
  const int wcn = wv & 1;     // 0..1 (N half: 64 cols)

  // T1: XCD-aware bijective block swizzle (gridDim.x = 1024, %8==0)
  const int cpx = gridDim.x >> 3;
  const int swz = ((int)blockIdx.x & 7) * cpx + ((int)blockIdx.x >> 3);
  const int bx = swz % NBX, by = swz / NBX;
  const long r0 = (long)by * 256;
  const long c0 = (long)bx * 128;

  // staging: wave wv, call j covers rows wv*32 + j*16 + (lane>>2) of a
  // 128-row unit, chunk (lane&3) ^ swz(row); swz(row) = ((lane>>2)&3)^((lane>>4)&3).
  const int srw = wv * 32 + (lane >> 2);
  const int sch = (lane & 3) ^ ((lane >> 2) & 3) ^ ((lane >> 4) & 3);
  const signed char* gAs = A + (r0 + srw) * (long)K + sch * 16;
  const signed char* gBs = Bm + (c0 + srw) * (long)K + sch * 16;
  const int wbase = wv * 2048;

  // fragment-read geometry (R10's): lane reads row base+frow, chunk kg^swz(frow)
  const int frow = lane & 15;
  const int fchunk = (lane >> 4) ^ (frow & 3) ^ ((frow >> 2) & 3);
  const int fbyte = frow * 64 + fchunk * 16;
  const int baseA = wr * 8192 + fbyte;    // + d*16384 + mh*4096
  const int baseB = wcn * 4096 + fbyte;   // + d*8192  + (second: +2048)

  int4v acc[8][4] = {};
  int4v af[4], bf0[2], bf1[2];
  const int nk = K >> 6;           // BK = 64 K-tiles
  const int nk2 = nk >> 1;

// stage A half h (128 rows) of K-tile t into dbuf d: 2 loads/thread
#define STGA(h, t, d) {                                                        \
    lds16(gAs + (long)((h) * 128) * K + (long)(t) * 64,                        \
          &smA[(d) * 16384 + (h) * 8192 + wbase + lane * 16]);                 \
    lds16(gAs + (long)((h) * 128 + 16) * K + (long)(t) * 64,                   \
          &smA[(d) * 16384 + (h) * 8192 + wbase + 1024 + lane * 16]); }
// stage B tile (128 rows) of K-tile t into dbuf d: 2 loads/thread
#define STGB(t, d) {                                                           \
    lds16(gBs + (long)(t) * 64,                                                \
          &smB[(d) * 8192 + wbase + lane * 16]);                               \
    lds16(gBs + (long)16 * K + (long)(t) * 64,                                 \
          &smB[(d) * 8192 + wbase + 1024 + lane * 16]); }
#define BAR  __builtin_amdgcn_s_barrier()
#define SCB  __builtin_amdgcn_sched_barrier(0)
#define LGKM0 asm volatile("s_waitcnt lgkmcnt(0)" ::: "memory")
#define PRIO1 __builtin_amdgcn_s_setprio(1)
#define PRIO0 __builtin_amdgcn_s_setprio(0)

  // prologue: t0 full (6 loads) + A-h0(t1) (2); drain t0 (leave 2); publish
  STGA(0, 0, 0); STGA(1, 0, 0); STGB(0, 0);
  STGA(0, 1, 1);
  asm volatile("s_waitcnt vmcnt(2)" ::: "memory");
  SCB; BAR; SCB;

  for (int i = 0; i < nk2; ++i) {
    const int t1 = 2 * i + 1;
    const int tn0 = 2 * i + 2;
    const int tn1 = 2 * i + 3;
    const bool s0 = tn0 < nk, s1 = tn1 < nk;

    // ---- P0: read A(buf0,mh0)+B(buf0,lo); stage A-h1(t1)->buf1; q(0,0)
    read_a4(smA, baseA, af);
    read_b2(smB, baseB, bf0);
    STGA(1, t1, 1);
    SCB; BAR; LGKM0; SCB;
    PRIO1; mfma_q(af, bf0, acc, 0, 0); PRIO0;
    SCB; BAR;

    // ---- P1: read B(buf0,hi); stage B(t1)->buf1; q(0,1)
    read_b2(smB, baseB + 2048, bf1);
    STGB(t1, 1);
    SCB; BAR; LGKM0; SCB;
    PRIO1; mfma_q(af, bf1, acc, 0, 2); PRIO0;
    SCB; BAR;

    // ---- P2: read A(buf0,mh1); q(1,1)
    read_a4(smA, baseA + 4096, af);
    SCB; BAR; LGKM0; SCB;
    PRIO1; mfma_q(af, bf1, acc, 4, 2); PRIO0;
    SCB; BAR;

    // ---- P3: stage A-h0(tn0)->buf0 (buf0 A reads ended P2); q(1,0); vmcnt
    if (s0) STGA(0, tn0, 0);
    SCB; BAR; SCB;
    PRIO1; mfma_q(af, bf0, acc, 4, 0); PRIO0;
    SCB;
    if (s0) { asm volatile("s_waitcnt vmcnt(2)" ::: "memory"); }
    else    { asm volatile("s_waitcnt vmcnt(0)" ::: "memory"); }
    SCB; BAR;

    // ---- P4: read A(buf1,mh0)+B(buf1,lo); stage A-h1(tn0)->buf0; q(0,0)
    read_a4(smA, 16384 + baseA, af);
    read_b2(smB, 8192 + baseB, bf0);
    if (s0) STGA(1, tn0, 0);
    SCB; BAR; LGKM0; SCB;
    PRIO1; mfma_q(af, bf0, acc, 0, 0); PRIO0;
    SCB; BAR;

    // ---- P5: read B(buf1,hi); stage B(tn0)->buf0; q(0,1)
    read_b2(smB, 8192 + baseB + 2048, bf1);
    if (s0) STGB(tn0, 0);
    SCB; BAR; LGKM0; SCB;
    PRIO1; mfma_q(af, bf1, acc, 0, 2); PRIO0;
    SCB; BAR;

    // ---- P6: read A(buf1,mh1); q(1,1)
    read_a4(smA, 16384 + baseA + 4096, af);
    SCB; BAR; LGKM0; SCB;
    PRIO1; mfma_q(af, bf1, acc, 4, 2); PRIO0;
    SCB; BAR;

    // ---- P7: stage A-h0(tn1)->buf1 (buf1 A reads ended P6); q(1,0); vmcnt
    if (s1) STGA(0, tn1, 1);
    SCB; BAR; SCB;
    PRIO1; mfma_q(af, bf0, acc, 4, 0); PRIO0;
    SCB;
    if (s1) { asm volatile("s_waitcnt vmcnt(2)" ::: "memory"); }
    else    { asm volatile("s_waitcnt vmcnt(0)" ::: "memory"); }
    SCB; BAR;
  }
#undef STGA
#undef STGB
#undef BAR
#undef SCB
#undef LGKM0
#undef PRIO1
#undef PRIO0

  // ---- epilogue ----
  const float sw = (float)fmax(meanw[0], 1e-5);
#pragma unroll
  for (int m = 0; m < 8; ++m) {
#pragma unroll
    for (int j = 0; j < 4; ++j) {
      const long row = r0 + wr * 128 + m * 16 + (lane >> 4) * 4 + j;
      const float sa = dsA[row] * sw;
#pragma unroll
      for (int n = 0; n < 4; ++n) {
        const long col = c0 + wcn * 64 + n * 16 + (lane & 15);
        float v = (float)acc[m][n][j] * sa + bias[col];
        if (EPI == 1) {
          float gl = 0.5f * v * (1.0f + erff(v * 0.70710678118654752f));
          outf[row * (long)N + col] = gl;
        } else {
          outf[row * (long)N + col] = v;
        }
      }
    }
  }
}

extern "C" void kernel_launch(void* const* d_in, const int* in_sizes, int n_in,
                              void* d_out, int out_size, void* d_ws, size_t ws_size,
                              hipStream_t stream) {
  const float* x     = (const float*)d_in[0];
  const float* gamma = (const float*)d_in[1];
  const float* beta  = (const float*)d_in[2];
  const float* w1    = (const float*)d_in[3];
  const float* b1    = (const float*)d_in[4];
  const float* w2    = (const float*)d_in[5];
  const float* b2    = (const float*)d_in[6];

  char* ws = (char*)d_ws;
  // meta (<256K): part1@0, part2@16K, means@32K, ds1@64K, ds2@128K
  // [1M)       wq  16M i8  (wq1, reused for wq2 after last GEMM1 chunk)
  // [1M+16M)   aq  32M i8
  // [1M+48M)   hq 128M i8  (dense quantized h)
  // peak 177 MiB.  d_out (128M) doubles as f32 GELU staging per M-chunk.
  double* part1 = (double*)(ws + 0);
  double* part2 = (double*)(ws + 16384);
  double* means = (double*)(ws + 32768);
  float* ds1  = (float*)(ws + 65536);
  float* ds2  = (float*)(ws + 131072);
  signed char* wq = (signed char*)(ws + 1048576l);
  signed char* aq = (signed char*)(ws + 17825792l);
  signed char* hq = (signed char*)(ws + 51380224l);

  const int NW = 16777216;  // elements in each weight matrix
  float* hstage = (float*)d_out;  // 4096 x 8192 f32 = 128 MiB, dead until GEMM2

  absmean_partial<<<2048, 256, 0, stream>>>(w1, NW, part1);
  absmean_partial<<<2048, 256, 0, stream>>>(w2, NW, part2);
  absmean_final<<<1, 256, 0, stream>>>(part1, 2048, (double)NW, means + 0);
  absmean_final<<<1, 256, 0, stream>>>(part2, 2048, (double)NW, means + 1);
  wquant_kernel<<<16384, 256, 0, stream>>>(w1, means + 0, wq, NW);
  ln_quant_kernel<<<16384, 256, 0, stream>>>(x, gamma, beta, aq, ds1);

  // GEMM1 in 4 M-chunks: f32 gelu -> d_out staging, requant -> dense i8 hq
  for (int c = 0; c < 4; ++c) {
    const long r0 = (long)c * MCHUNK;
    gemm256_kernel<1><<<(H_DIM / 128) * (MCHUNK / 256), 256, 0, stream>>>(
        aq + r0 * D_DIM, wq, ds1 + r0, means + 0, b1, hstage,
        H_DIM / 128, H_DIM, D_DIM);
    hquant32_kernel<<<MCHUNK, 256, 0, stream>>>(
        hstage, hq + r0 * H_DIM, ds2 + r0);
  }

  // wq slot now free: quantize w2 into it
  wquant_kernel<<<16384, 256, 0, stream>>>(w2, means + 1, wq, NW);

  // GEMM2: out = hq . wq2^T * (ds2*sw2) + b2
  gemm256_kernel<2><<<(D_DIM / 128) * (M_DIM / 256), 256, 0, stream>>>(
      hq, wq, ds2, means + 1, b2, (float*)d_out,
      D_DIM / 128, D_DIM, H_DIM);
}

// Round 14
// 1094.484 us; speedup vs baseline: 1.0120x; 1.0120x over previous
//
#include <hip/hip_runtime.h>
#include <hip/hip_bf16.h>

// BitNet FFN: LN -> act_quant/ternary-W matmul -> GELU(erf) -> act_quant/ternary-W matmul
// Shapes: x[4,4096,2048] f32, w1[8192,2048], w2[2048,8192], out [16384,2048] f32.
// R14: R10 geometry (256x256, 512 thr, 64KB LDS, chunk-XOR layout) with the
// K-loop collapsed to ONE barrier per K-tile: {12 ds_reads -> counted lgkm
// interleaved with 4 MFMA quadrants -> vmcnt(0) (waits loads issued a full
// iteration earlier, ~free) -> barrier -> stage t+2}. Removes 3 barriers/K-tile
// and creates one long scheduling region so the 2 waves/SIMD can skew (one
// wave's MFMAs overlap the other's LDS reads). R13's 2-block split reverted
// (regressed: extra staging traffic, no desync benefit).
// i8 MFMA 16x16x64; i32 accum exact -> output bit-identical (absmax 2.539e-2).
// Peak ws 177 MiB; d_out doubles as f32 GELU staging per M-chunk.

typedef __attribute__((ext_vector_type(4))) int int4v;

#define D_DIM 2048
#define H_DIM 8192
#define M_DIM 16384
#define MCHUNK 4096

// ---------- small helpers ----------
__device__ __forceinline__ float block_sum(float v, float* buf) {
#pragma unroll
  for (int o = 32; o > 0; o >>= 1) v += __shfl_down(v, o, 64);
  const int lane = threadIdx.x & 63, w = threadIdx.x >> 6;
  if (lane == 0) buf[w] = v;
  __syncthreads();
  float r = buf[0] + buf[1] + buf[2] + buf[3];
  __syncthreads();
  return r;
}
__device__ __forceinline__ float block_max(float v, float* buf) {
#pragma unroll
  for (int o = 32; o > 0; o >>= 1) v = fmaxf(v, __shfl_down(v, o, 64));
  const int lane = threadIdx.x & 63, w = threadIdx.x >> 6;
  if (lane == 0) buf[w] = v;
  __syncthreads();
  float r = fmaxf(fmaxf(buf[0], buf[1]), fmaxf(buf[2], buf[3]));
  __syncthreads();
  return r;
}

__device__ __forceinline__ void lds16(const signed char* g, signed char* l) {
  __builtin_amdgcn_global_load_lds(
      (const __attribute__((address_space(1))) unsigned int*)g,
      (__attribute__((address_space(3))) unsigned int*)l, 16, 0, 0);
}

// ---------- weight abs-mean (deterministic two-stage) ----------
__global__ __launch_bounds__(256) void absmean_partial(const float* __restrict__ w,
                                                       int n, double* __restrict__ part) {
  __shared__ float buf[4];
  float s = 0.0f;
  const long stride = (long)gridDim.x * 256 * 4;
  for (long i = ((long)blockIdx.x * 256 + threadIdx.x) * 4; i < n; i += stride) {
    float4 v = *(const float4*)(w + i);
    s += fabsf(v.x) + fabsf(v.y) + fabsf(v.z) + fabsf(v.w);
  }
  float r = block_sum(s, buf);
  if (threadIdx.x == 0) part[blockIdx.x] = (double)r;
}

__global__ __launch_bounds__(256) void absmean_final(const double* __restrict__ part,
                                                     int nb, double n, double* __restrict__ out) {
  __shared__ double buf[4];
  double s = 0.0;
  for (int i = threadIdx.x; i < nb; i += 256) s += part[i];
#pragma unroll
  for (int o = 32; o > 0; o >>= 1) s += __shfl_down(s, o, 64);
  const int lane = threadIdx.x & 63, w = threadIdx.x >> 6;
  if (lane == 0) buf[w] = s;
  __syncthreads();
  if (threadIdx.x == 0) out[0] = (buf[0] + buf[1] + buf[2] + buf[3]) / n;
}

// ---------- ternary weight quant -> i8 {-1,0,1} ----------
__global__ __launch_bounds__(256) void wquant_kernel(const float* __restrict__ w,
                                                     const double* __restrict__ mean,
                                                     signed char* __restrict__ wq, int n) {
  long i = ((long)blockIdx.x * 256 + threadIdx.x) * 4;
  if (i >= n) return;
  const float s = 1.0f / (float)fmax(mean[0], 1e-5);
  float4 v = *(const float4*)(w + i);
  __align__(4) signed char q[4];
  q[0] = (signed char)(int)fminf(fmaxf(rintf(v.x * s), -1.f), 1.f);
  q[1] = (signed char)(int)fminf(fmaxf(rintf(v.y * s), -1.f), 1.f);
  q[2] = (signed char)(int)fminf(fmaxf(rintf(v.z * s), -1.f), 1.f);
  q[3] = (signed char)(int)fminf(fmaxf(rintf(v.w * s), -1.f), 1.f);
  *(int*)(wq + i) = *(int*)q;
}

// ---------- fused LayerNorm + per-token int8 absmax quant -> i8 ----------
__global__ __launch_bounds__(256) void ln_quant_kernel(const float* __restrict__ x,
                                                       const float* __restrict__ gamma,
                                                       const float* __restrict__ beta,
                                                       signed char* __restrict__ aq,
                                                       float* __restrict__ ds) {
  __shared__ float buf[4];
  const int t = threadIdx.x;
  const long row = blockIdx.x;
  const float* xr = x + row * (long)D_DIM;
  float v[8];
  *(float4*)(v)     = *(const float4*)(xr + t * 8);
  *(float4*)(v + 4) = *(const float4*)(xr + t * 8 + 4);
  float s = 0.f;
#pragma unroll
  for (int i = 0; i < 8; ++i) s += v[i];
  s = block_sum(s, buf);
  const float mu = s * (1.0f / 2048.0f);
  float sq = 0.f;
#pragma unroll
  for (int i = 0; i < 8; ++i) { float d = v[i] - mu; sq += d * d; }
  sq = block_sum(sq, buf);
  const float inv = 1.0f / sqrtf(sq * (1.0f / 2048.0f) + 1e-5f);
  float gam[8], bet[8];
  *(float4*)(gam)     = *(const float4*)(gamma + t * 8);
  *(float4*)(gam + 4) = *(const float4*)(gamma + t * 8 + 4);
  *(float4*)(bet)     = *(const float4*)(beta + t * 8);
  *(float4*)(bet + 4) = *(const float4*)(beta + t * 8 + 4);
  float xn[8]; float am = 0.f;
#pragma unroll
  for (int i = 0; i < 8; ++i) {
    xn[i] = (v[i] - mu) * inv * gam[i] + bet[i];
    am = fmaxf(am, fabsf(xn[i]));
  }
  am = block_max(am, buf);
  am = fmaxf(am, 1e-5f);
  const float qs = 127.0f / am;
  __align__(8) signed char q[8];
#pragma unroll
  for (int i = 0; i < 8; ++i)
    q[i] = (signed char)(int)fminf(fmaxf(rintf(xn[i] * qs), -128.f), 127.f);
  *(long*)(aq + row * D_DIM + t * 8) = *(long*)q;
  if (t == 0) ds[row] = am / 127.0f;
}

// ---------- per-token re-quant from f32 h chunk -> dense i8 ----------
__global__ __launch_bounds__(256) void hquant32_kernel(const float* __restrict__ src,
                                                       signed char* __restrict__ dst,
                                                       float* __restrict__ ds2) {
  __shared__ float buf[4];
  const int t = threadIdx.x;
  const long row = blockIdx.x;
  const float* sr = src + row * (long)H_DIM;
  float v[4][8];
#pragma unroll
  for (int c = 0; c < 4; ++c) {
    *(float4*)(v[c])     = *(const float4*)(sr + (c * 256 + t) * 8);
    *(float4*)(v[c] + 4) = *(const float4*)(sr + (c * 256 + t) * 8 + 4);
  }
  float am = 0.f;
#pragma unroll
  for (int c = 0; c < 4; ++c)
#pragma unroll
    for (int i = 0; i < 8; ++i) am = fmaxf(am, fabsf(v[c][i]));
  am = block_max(am, buf);
  am = fmaxf(am, 1e-5f);
  const float qs = 127.0f / am;
  signed char* dr = dst + row * (long)H_DIM;
#pragma unroll
  for (int c = 0; c < 4; ++c) {
    __align__(8) signed char o[8];
#pragma unroll
    for (int i = 0; i < 8; ++i)
      o[i] = (signed char)(int)fminf(fmaxf(rintf(v[c][i] * qs), -128.f), 127.f);
    *(long*)(dr + (c * 256 + t) * 8) = *(long*)o;
  }
  if (t == 0) ds2[row] = am / 127.0f;
}

// ---------- subtile readers / MFMA quadrant (i8, K=64 per instr) ----------
__device__ __forceinline__ void read_a4(const signed char* sm, int base, int4v (&af)[4]) {
#pragma unroll
  for (int ms = 0; ms < 4; ++ms)
    af[ms] = *(const int4v*)&sm[base + ms * 1024];   // 16 rows * 64B
}
__device__ __forceinline__ void read_b2(const signed char* sm, int base, int4v (&bf)[2]) {
#pragma unroll
  for (int ns = 0; ns < 2; ++ns)
    bf[ns] = *(const int4v*)&sm[base + ns * 1024];
}
__device__ __forceinline__ void mfma_q(const int4v (&af)[4], const int4v (&bf)[2],
                                       int4v (&acc)[8][4], int m0, int n0) {
#pragma unroll
  for (int ms = 0; ms < 4; ++ms)
#pragma unroll
    for (int ns = 0; ns < 2; ++ns)
      acc[m0 + ms][n0 + ns] = __builtin_amdgcn_mfma_i32_16x16x64_i8(
          af[ms], bf[ns], acc[m0 + ms][n0 + ns], 0, 0, 0);
}

// ---------- 256x256 BK=64 single-barrier-per-K-tile i8 GEMM, A[M,K] x B[N,K]^T ----------
// 8 waves (2M x 4N); double-buffered 64KiB LDS total.
// Byte layout per matrix: [dbuf 16384B][half 8192B][row 0..127][64B row],
// chunk-XOR swizzle: LDS[row][p] = global[row][p ^ (row&3)^((row>>2)&3)],
// applied on pre-swizzled global source AND ds_read side (rule #21; R10's).
// Per K-tile: issue 12 ds_reads -> lgkm(6)/(4)/(0) + 4 MFMA quadrants ->
// vmcnt(0) (t+1's loads, 1 iteration old, ~free) -> barrier -> stage t+2.
// EPI==1: dequant+bias+exact GELU -> f32.  EPI==2: dequant+bias -> f32.
template <int EPI>
__global__ __launch_bounds__(512, 2) void gemm256_kernel(
    const signed char* __restrict__ A,
    const signed char* __restrict__ Bm,
    const float* __restrict__ dsA,
    const double* __restrict__ meanw,
    const float* __restrict__ bias,
    float* __restrict__ outf,
    int NBX, int N, int K) {
  __shared__ __align__(16) signed char smA[2 * 256 * 64];
  __shared__ __align__(16) signed char smB[2 * 256 * 64];
  const int tid = threadIdx.x;
  const int lane = tid & 63;
  const int wid = tid >> 6;
  const int wr = wid >> 2;    // 0..1 (M half: 128 rows)
  const int wcn = wid & 3;    // 0..3 (N quarter: 64 cols)

  // T1: XCD-aware bijective block swizzle (gridDim.x % 8 == 0 here: 512)
  const int cpx = gridDim.x >> 3;
  const int swz = ((int)blockIdx.x & 7) * cpx + ((int)blockIdx.x >> 3);
  const int bx = swz % NBX, by = swz / NBX;
  const long r0 = (long)by * 256;
  const long c0 = (long)bx * 256;

  // staging geometry: half-tile = 128 rows x 64B = 8KB = 512 threads x 16B.
  // thread t -> (row = t>>2, chunk = t&3); source chunk pre-swizzled.
  const int srow = tid >> 2;
  const int schunk = (tid & 3) ^ (srow & 3) ^ ((srow >> 2) & 3);
  const signed char* gAs = A + (r0 + srow) * (long)K + schunk * 16;
  const signed char* gBs = Bm + (c0 + srow) * (long)K + schunk * 16;

  // fragment-read geometry: lane reads row (base+frow), 16B chunk (lane>>4)^swz
  const int frow = lane & 15;
  const int fchunk = (lane >> 4) ^ (frow & 3) ^ ((frow >> 2) & 3);
  const int fbyte = frow * 64 + fchunk * 16;
  const int baseA = wr * 8192 + fbyte;                             // + d*16384 + mh*4096
  const int baseB = (wcn >> 1) * 8192 + (wcn & 1) * 4096 + fbyte;  // + d*16384 + nh*2048

  int4v acc[8][4] = {};
  int4v afLo[4], afHi[4], bf0[2], bf1[2];
  const int nk = K >> 6;           // BK = 64 K-tiles

// stage half-tile h of K-tile t into dbuf d (1 global_load_lds per thread)
#define STG(gbase, h, t, smbase, d)                                           \
    lds16((gbase) + (long)((h) * 128) * K + (long)(t) * 64,                   \
          &(smbase)[(d) * 16384 + (h) * 8192 + tid * 16]);
#define BAR  __builtin_amdgcn_s_barrier()
#define SCB  __builtin_amdgcn_sched_barrier(0)
#define PRIO1 __builtin_amdgcn_s_setprio(1)
#define PRIO0 __builtin_amdgcn_s_setprio(0)

  // prologue: t0 -> buf0 (4 loads), t1 -> buf1 (4 loads); wait t0; publish
  STG(gAs, 0, 0, smA, 0); STG(gAs, 1, 0, smA, 0);
  STG(gBs, 0, 0, smB, 0); STG(gBs, 1, 0, smB, 0);
  STG(gAs, 0, 1, smA, 1); STG(gAs, 1, 1, smA, 1);
  STG(gBs, 0, 1, smB, 1); STG(gBs, 1, 1, smB, 1);
  asm volatile("s_waitcnt vmcnt(4)" ::: "memory");
  SCB; BAR; SCB;

  for (int t = 0; t < nk; ++t) {
    const int c = t & 1;
    const int off = c * 16384;

    // issue all 12 subtile reads (issue order: A-lo x4, B-lo x2, B-hi x2, A-hi x4)
    read_a4(smA, off + baseA, afLo);
    read_b2(smB, off + baseB, bf0);
    read_b2(smB, off + baseB + 2048, bf1);
    read_a4(smA, off + baseA + 4096, afHi);
    SCB;
    // A-lo + B-lo landed (in-order DS retire; <=6 outstanding = B-hi + A-hi)
    asm volatile("s_waitcnt lgkmcnt(6)" ::: "memory"); SCB;
    PRIO1; mfma_q(afLo, bf0, acc, 0, 0); PRIO0; SCB;
    // B-hi landed
    asm volatile("s_waitcnt lgkmcnt(4)" ::: "memory"); SCB;
    PRIO1; mfma_q(afLo, bf1, acc, 0, 2); PRIO0; SCB;
    // A-hi landed
    asm volatile("s_waitcnt lgkmcnt(0)" ::: "memory"); SCB;
    PRIO1; mfma_q(afHi, bf1, acc, 4, 2); mfma_q(afHi, bf0, acc, 4, 0); PRIO0; SCB;

    // t+1's 4 loads (issued one full iteration ago) -> ~free drain; publish.
    asm volatile("s_waitcnt vmcnt(0)" ::: "memory"); SCB;
    BAR; SCB;

    // stage t+2 into buf c (all waves done reading c at the barrier above)
    if (t + 2 < nk) {
      STG(gAs, 0, t + 2, smA, c); STG(gAs, 1, t + 2, smA, c);
      STG(gBs, 0, t + 2, smB, c); STG(gBs, 1, t + 2, smB, c);
    }
  }
#undef STG
#undef BAR
#undef SCB
#undef PRIO1
#undef PRIO0

  // ---- epilogue ----
  const float sw = (float)fmax(meanw[0], 1e-5);
#pragma unroll
  for (int m = 0; m < 8; ++m) {
#pragma unroll
    for (int j = 0; j < 4; ++j) {
      const long row = r0 + wr * 128 + m * 16 + (lane >> 4) * 4 + j;
      const float sa = dsA[row] * sw;
#pragma unroll
      for (int n = 0; n < 4; ++n) {
        const long col = c0 + wcn * 64 + n * 16 + (lane & 15);
        float v = (float)acc[m][n][j] * sa + bias[col];
        if (EPI == 1) {
          float gl = 0.5f * v * (1.0f + erff(v * 0.70710678118654752f));
          outf[row * (long)N + col] = gl;
        } else {
          outf[row * (long)N + col] = v;
        }
      }
    }
  }
}

extern "C" void kernel_launch(void* const* d_in, const int* in_sizes, int n_in,
                              void* d_out, int out_size, void* d_ws, size_t ws_size,
                              hipStream_t stream) {
  const float* x     = (const float*)d_in[0];
  const float* gamma = (const float*)d_in[1];
  const float* beta  = (const float*)d_in[2];
  const float* w1    = (const float*)d_in[3];
  const float* b1    = (const float*)d_in[4];
  const float* w2    = (const float*)d_in[5];
  const float* b2    = (const float*)d_in[6];

  char* ws = (char*)d_ws;
  // meta (<256K): part1@0, part2@16K, means@32K, ds1@64K, ds2@128K
  // [1M)       wq  16M i8  (wq1, reused for wq2 after last GEMM1 chunk)
  // [1M+16M)   aq  32M i8
  // [1M+48M)   hq 128M i8  (dense quantized h)
  // peak 177 MiB.  d_out (128M) doubles as f32 GELU staging per M-chunk.
  double* part1 = (double*)(ws + 0);
  double* part2 = (double*)(ws + 16384);
  double* means = (double*)(ws + 32768);
  float* ds1  = (float*)(ws + 65536);
  float* ds2  = (float*)(ws + 131072);
  signed char* wq = (signed char*)(ws + 1048576l);
  signed char* aq = (signed char*)(ws + 17825792l);
  signed char* hq = (signed char*)(ws + 51380224l);

  const int NW = 16777216;  // elements in each weight matrix
  float* hstage = (float*)d_out;  // 4096 x 8192 f32 = 128 MiB, dead until GEMM2

  absmean_partial<<<2048, 256, 0, stream>>>(w1, NW, part1);
  absmean_partial<<<2048, 256, 0, stream>>>(w2, NW, part2);
  absmean_final<<<1, 256, 0, stream>>>(part1, 2048, (double)NW, means + 0);
  absmean_final<<<1, 256, 0, stream>>>(part2, 2048, (double)NW, means + 1);
  wquant_kernel<<<16384, 256, 0, stream>>>(w1, means + 0, wq, NW);
  ln_quant_kernel<<<16384, 256, 0, stream>>>(x, gamma, beta, aq, ds1);

  // GEMM1 in 4 M-chunks: f32 gelu -> d_out staging, requant -> dense i8 hq
  for (int c = 0; c < 4; ++c) {
    const long r0 = (long)c * MCHUNK;
    gemm256_kernel<1><<<(H_DIM / 256) * (MCHUNK / 256), 512, 0, stream>>>(
        aq + r0 * D_DIM, wq, ds1 + r0, means + 0, b1, hstage,
        H_DIM / 256, H_DIM, D_DIM);
    hquant32_kernel<<<MCHUNK, 256, 0, stream>>>(
        hstage, hq + r0 * H_DIM, ds2 + r0);
  }

  // wq slot now free: quantize w2 into it
  wquant_kernel<<<16384, 256, 0, stream>>>(w2, means + 1, wq, NW);

  // GEMM2: out = hq . wq2^T * (ds2*sw2) + b2
  gemm256_kernel<2><<<(D_DIM / 256) * (M_DIM / 256), 512, 0, stream>>>(
      hq, wq, ds2, means + 1, b2, (float*)d_out,
      D_DIM / 256, D_DIM, H_DIM);
}

// Round 18
// 988.010 us; speedup vs baseline: 1.1211x; 1.1078x over previous
//
#include <hip/hip_runtime.h>
#include <hip/hip_bf16.h>

// BitNet FFN: LN -> act_quant/ternary-W matmul -> GELU(erf) -> act_quant/ternary-W matmul
// Shapes: x[4,4096,2048] f32, w1[8192,2048], w2[2048,8192], out [16384,2048] f32.
// R18: GEMM = R10 VERBATIM (best passing config: 989us total, GEMM2 311us).
// B-direct experiments (R15-R17) abandoned: 3x correctness failures on the
// mixed vmcnt-queue ledger. Launcher-only wins: w2 quantized upfront into its
// own slot (removes mid-pipeline wquant serialization; ws 193MB < proven
// 385MB), absmean partial/final pairs merged (grid-partitioned). 13 dispatches
// vs 15. i8 MFMA 16x16x64; i32 accum exact -> output bit-identical
// (absmax 2.539e-2 canary). d_out doubles as f32 GELU staging per M-chunk.

typedef __attribute__((ext_vector_type(4))) int int4v;

#define D_DIM 2048
#define H_DIM 8192
#define M_DIM 16384
#define MCHUNK 4096

// ---------- small helpers ----------
__device__ __forceinline__ float block_sum(float v, float* buf) {
#pragma unroll
  for (int o = 32; o > 0; o >>= 1) v += __shfl_down(v, o, 64);
  const int lane = threadIdx.x & 63, w = threadIdx.x >> 6;
  if (lane == 0) buf[w] = v;
  __syncthreads();
  float r = buf[0] + buf[1] + buf[2] + buf[3];
  __syncthreads();
  return r;
}
__device__ __forceinline__ float block_max(float v, float* buf) {
#pragma unroll
  for (int o = 32; o > 0; o >>= 1) v = fmaxf(v, __shfl_down(v, o, 64));
  const int lane = threadIdx.x & 63, w = threadIdx.x >> 6;
  if (lane == 0) buf[w] = v;
  __syncthreads();
  float r = fmaxf(fmaxf(buf[0], buf[1]), fmaxf(buf[2], buf[3]));
  __syncthreads();
  return r;
}

__device__ __forceinline__ void lds16(const signed char* g, signed char* l) {
  __builtin_amdgcn_global_load_lds(
      (const __attribute__((address_space(1))) unsigned int*)g,
      (__attribute__((address_space(3))) unsigned int*)l, 16, 0, 0);
}

// ---------- weight abs-mean, both matrices in one dispatch ----------
__global__ __launch_bounds__(256) void absmean_partial2(const float* __restrict__ w1,
                                                        const float* __restrict__ w2,
                                                        int n, double* __restrict__ part1,
                                                        double* __restrict__ part2) {
  __shared__ float buf[4];
  const int half = gridDim.x >> 1;
  const bool second = (int)blockIdx.x >= half;
  const float* w = second ? w2 : w1;
  double* part = second ? part2 : part1;
  const int bid = second ? (blockIdx.x - half) : blockIdx.x;
  float s = 0.0f;
  const long stride = (long)half * 256 * 4;
  for (long i = ((long)bid * 256 + threadIdx.x) * 4; i < n; i += stride) {
    float4 v = *(const float4*)(w + i);
    s += fabsf(v.x) + fabsf(v.y) + fabsf(v.z) + fabsf(v.w);
  }
  float r = block_sum(s, buf);
  if (threadIdx.x == 0) part[bid] = (double)r;
}

__global__ __launch_bounds__(256) void absmean_final2(const double* __restrict__ part1,
                                                      const double* __restrict__ part2,
                                                      int nb, double n,
                                                      double* __restrict__ out) {
  __shared__ double buf[4];
  const double* part = (blockIdx.x == 0) ? part1 : part2;
  double s = 0.0;
  for (int i = threadIdx.x; i < nb; i += 256) s += part[i];
#pragma unroll
  for (int o = 32; o > 0; o >>= 1) s += __shfl_down(s, o, 64);
  const int lane = threadIdx.x & 63, w = threadIdx.x >> 6;
  if (lane == 0) buf[w] = s;
  __syncthreads();
  if (threadIdx.x == 0) out[blockIdx.x] = (buf[0] + buf[1] + buf[2] + buf[3]) / n;
}

// ---------- ternary weight quant -> i8 {-1,0,1}, both matrices ----------
__global__ __launch_bounds__(256) void wquant2_kernel(const float* __restrict__ w1,
                                                      const float* __restrict__ w2,
                                                      const double* __restrict__ means,
                                                      signed char* __restrict__ wq1,
                                                      signed char* __restrict__ wq2, int n) {
  const int half = gridDim.x >> 1;
  const bool second = (int)blockIdx.x >= half;
  const float* w = second ? w2 : w1;
  signed char* wq = second ? wq2 : wq1;
  const double mean = second ? means[1] : means[0];
  const int bid = second ? (blockIdx.x - half) : blockIdx.x;
  long i = ((long)bid * 256 + threadIdx.x) * 4;
  if (i >= n) return;
  const float s = 1.0f / (float)fmax(mean, 1e-5);
  float4 v = *(const float4*)(w + i);
  __align__(4) signed char q[4];
  q[0] = (signed char)(int)fminf(fmaxf(rintf(v.x * s), -1.f), 1.f);
  q[1] = (signed char)(int)fminf(fmaxf(rintf(v.y * s), -1.f), 1.f);
  q[2] = (signed char)(int)fminf(fmaxf(rintf(v.z * s), -1.f), 1.f);
  q[3] = (signed char)(int)fminf(fmaxf(rintf(v.w * s), -1.f), 1.f);
  *(int*)(wq + i) = *(int*)q;
}

// ---------- fused LayerNorm + per-token int8 absmax quant -> i8 ----------
__global__ __launch_bounds__(256) void ln_quant_kernel(const float* __restrict__ x,
                                                       const float* __restrict__ gamma,
                                                       const float* __restrict__ beta,
                                                       signed char* __restrict__ aq,
                                                       float* __restrict__ ds) {
  __shared__ float buf[4];
  const int t = threadIdx.x;
  const long row = blockIdx.x;
  const float* xr = x + row * (long)D_DIM;
  float v[8];
  *(float4*)(v)     = *(const float4*)(xr + t * 8);
  *(float4*)(v + 4) = *(const float4*)(xr + t * 8 + 4);
  float s = 0.f;
#pragma unroll
  for (int i = 0; i < 8; ++i) s += v[i];
  s = block_sum(s, buf);
  const float mu = s * (1.0f / 2048.0f);
  float sq = 0.f;
#pragma unroll
  for (int i = 0; i < 8; ++i) { float d = v[i] - mu; sq += d * d; }
  sq = block_sum(sq, buf);
  const float inv = 1.0f / sqrtf(sq * (1.0f / 2048.0f) + 1e-5f);
  float gam[8], bet[8];
  *(float4*)(gam)     = *(const float4*)(gamma + t * 8);
  *(float4*)(gam + 4) = *(const float4*)(gamma + t * 8 + 4);
  *(float4*)(bet)     = *(const float4*)(beta + t * 8);
  *(float4*)(bet + 4) = *(const float4*)(beta + t * 8 + 4);
  float xn[8]; float am = 0.f;
#pragma unroll
  for (int i = 0; i < 8; ++i) {
    xn[i] = (v[i] - mu) * inv * gam[i] + bet[i];
    am = fmaxf(am, fabsf(xn[i]));
  }
  am = block_max(am, buf);
  am = fmaxf(am, 1e-5f);
  const float qs = 127.0f / am;
  __align__(8) signed char q[8];
#pragma unroll
  for (int i = 0; i < 8; ++i)
    q[i] = (signed char)(int)fminf(fmaxf(rintf(xn[i] * qs), -128.f), 127.f);
  *(long*)(aq + row * D_DIM + t * 8) = *(long*)q;
  if (t == 0) ds[row] = am / 127.0f;
}

// ---------- per-token re-quant from f32 h chunk -> dense i8 ----------
__global__ __launch_bounds__(256) void hquant32_kernel(const float* __restrict__ src,
                                                       signed char* __restrict__ dst,
                                                       float* __restrict__ ds2) {
  __shared__ float buf[4];
  const int t = threadIdx.x;
  const long row = blockIdx.x;
  const float* sr = src + row * (long)H_DIM;
  float v[4][8];
#pragma unroll
  for (int c = 0; c < 4; ++c) {
    *(float4*)(v[c])     = *(const float4*)(sr + (c * 256 + t) * 8);
    *(float4*)(v[c] + 4) = *(const float4*)(sr + (c * 256 + t) * 8 + 4);
  }
  float am = 0.f;
#pragma unroll
  for (int c = 0; c < 4; ++c)
#pragma unroll
    for (int i = 0; i < 8; ++i) am = fmaxf(am, fabsf(v[c][i]));
  am = block_max(am, buf);
  am = fmaxf(am, 1e-5f);
  const float qs = 127.0f / am;
  signed char* dr = dst + row * (long)H_DIM;
#pragma unroll
  for (int c = 0; c < 4; ++c) {
    __align__(8) signed char o[8];
#pragma unroll
    for (int i = 0; i < 8; ++i)
      o[i] = (signed char)(int)fminf(fmaxf(rintf(v[c][i] * qs), -128.f), 127.f);
    *(long*)(dr + (c * 256 + t) * 8) = *(long*)o;
  }
  if (t == 0) ds2[row] = am / 127.0f;
}

// ---------- subtile readers / MFMA quadrant (i8, K=64 per instr) ----------
__device__ __forceinline__ void read_a4(const signed char* sm, int base, int4v (&af)[4]) {
#pragma unroll
  for (int ms = 0; ms < 4; ++ms)
    af[ms] = *(const int4v*)&sm[base + ms * 1024];   // 16 rows * 64B
}
__device__ __forceinline__ void read_b2(const signed char* sm, int base, int4v (&bf)[2]) {
#pragma unroll
  for (int ns = 0; ns < 2; ++ns)
    bf[ns] = *(const int4v*)&sm[base + ns * 1024];
}
__device__ __forceinline__ void mfma_q(const int4v (&af)[4], const int4v (&bf)[2],
                                       int4v (&acc)[8][4], int m0, int n0) {
#pragma unroll
  for (int ms = 0; ms < 4; ++ms)
#pragma unroll
    for (int ns = 0; ns < 2; ++ns)
      acc[m0 + ms][n0 + ns] = __builtin_amdgcn_mfma_i32_16x16x64_i8(
          af[ms], bf[ns], acc[m0 + ms][n0 + ns], 0, 0, 0);
}

// ---------- 256x256 BK=64 8-phase i8 GEMM, A[M,K] x B[N,K]^T (R10 verbatim) ----------
// 8 waves (2M x 4N); double-buffered 64KiB LDS total.
// Byte layout per matrix: [dbuf 16384B][half 8192B][row 0..127][64B row].
// LDS swizzle: chunk ^= (row&3)^((row>>2)&3) (<=2-way, free); applied on the
// pre-swizzled global source AND the ds_read side (rule #21).
// Iteration = 2 K-tiles, 8 phases; 1 load per STG; vmcnt(1) at P3/P7.
// EPI==1: dequant+bias+exact GELU -> f32.  EPI==2: dequant+bias -> f32.
template <int EPI>
__global__ __launch_bounds__(512, 2) void gemm256_kernel(
    const signed char* __restrict__ A,
    const signed char* __restrict__ Bm,
    const float* __restrict__ dsA,
    const double* __restrict__ meanw,
    const float* __restrict__ bias,
    float* __restrict__ outf,
    int NBX, int N, int K) {
  __shared__ __align__(16) signed char smA[2 * 256 * 64];
  __shared__ __align__(16) signed char smB[2 * 256 * 64];
  const int tid = threadIdx.x;
  const int lane = tid & 63;
  const int wid = tid >> 6;
  const int wr = wid >> 2;    // 0..1 (M half: 128 rows)
  const int wcn = wid & 3;    // 0..3 (N quarter: 64 cols)

  // T1: XCD-aware bijective block swizzle (gridDim.x % 8 == 0 here: 512)
  const int cpx = gridDim.x >> 3;
  const int swz = ((int)blockIdx.x & 7) * cpx + ((int)blockIdx.x >> 3);
  const int bx = swz % NBX, by = swz / NBX;
  const long r0 = (long)by * 256;
  const long c0 = (long)bx * 256;

  // staging geometry: half-tile = 128 rows x 64B = 8KB = 512 threads x 16B.
  // thread t -> (row = t>>2, chunk = t&3); source chunk pre-swizzled.
  const int srow = tid >> 2;
  const int schunk = (tid & 3) ^ (srow & 3) ^ ((srow >> 2) & 3);
  const signed char* gAs = A + (r0 + srow) * (long)K + schunk * 16;
  const signed char* gBs = Bm + (c0 + srow) * (long)K + schunk * 16;

  // fragment-read geometry: lane reads row (base+frow), 16B chunk (lane>>4)^swz
  const int frow = lane & 15;
  const int fchunk = (lane >> 4) ^ (frow & 3) ^ ((frow >> 2) & 3);
  const int fbyte = frow * 64 + fchunk * 16;
  const int baseA = wr * 8192 + fbyte;                             // + d*16384 + mh*4096
  const int baseB = (wcn >> 1) * 8192 + (wcn & 1) * 4096 + fbyte;  // + d*16384 + nh*2048

  int4v acc[8][4] = {};
  int4v af[4], bf0[2], bf1[2];
  const int nk = K >> 6;           // BK = 64 K-tiles
  const int nk2 = nk >> 1;

// stage half-tile h of K-tile t into dbuf d (1 global_load_lds per thread)
#define STG(gbase, h, t, smbase, d)                                           \
    lds16((gbase) + (long)((h) * 128) * K + (long)(t) * 64,                   \
          &(smbase)[(d) * 16384 + (h) * 8192 + tid * 16]);
#define BAR  __builtin_amdgcn_s_barrier()
#define SCB  __builtin_amdgcn_sched_barrier(0)
#define LGKM0 asm volatile("s_waitcnt lgkmcnt(0)" ::: "memory")
#define PRIO1 __builtin_amdgcn_s_setprio(1)
#define PRIO0 __builtin_amdgcn_s_setprio(0)

  // prologue: t0 full (4 loads) + A-h0(t1); drain t0 (leave 1); publish
  STG(gAs, 0, 0, smA, 0); STG(gAs, 1, 0, smA, 0);
  STG(gBs, 0, 0, smB, 0); STG(gBs, 1, 0, smB, 0);
  STG(gAs, 0, 1, smA, 1);
  asm volatile("s_waitcnt vmcnt(1)" ::: "memory");
  SCB; BAR; SCB;

  for (int i = 0; i < nk2; ++i) {
    const int t1 = 2 * i + 1;
    const int tn0 = 2 * i + 2;
    const int tn1 = 2 * i + 3;
    const bool s0 = tn0 < nk, s1 = tn1 < nk;

    // ---- P0: read A(buf0,mh0)+B(buf0,nh0); stage A-h1(t1)->buf1; q(0,0)
    read_a4(smA, baseA, af);
    read_b2(smB, baseB, bf0);
    STG(gAs, 1, t1, smA, 1);
    SCB; BAR; LGKM0; SCB;
    PRIO1; mfma_q(af, bf0, acc, 0, 0); PRIO0;
    SCB; BAR;

    // ---- P1: read B(buf0,nh1); stage B-h0(t1)->buf1; q(0,1)
    read_b2(smB, baseB + 2048, bf1);
    STG(gBs, 0, t1, smB, 1);
    SCB; BAR; LGKM0; SCB;
    PRIO1; mfma_q(af, bf1, acc, 0, 2); PRIO0;
    SCB; BAR;

    // ---- P2: read A(buf0,mh1); stage B-h1(t1)->buf1; q(1,1)
    read_a4(smA, baseA + 4096, af);
    STG(gBs, 1, t1, smB, 1);
    SCB; BAR; LGKM0; SCB;
    PRIO1; mfma_q(af, bf1, acc, 4, 2); PRIO0;
    SCB; BAR;

    // ---- P3: stage A-h0(tn0)->buf0 (buf0 reads ended P2); q(1,0); vmcnt
    if (s0) STG(gAs, 0, tn0, smA, 0);
    SCB; BAR; SCB;
    PRIO1; mfma_q(af, bf0, acc, 4, 0); PRIO0;
    SCB;
    if (s0) { asm volatile("s_waitcnt vmcnt(1)" ::: "memory"); }
    else    { asm volatile("s_waitcnt vmcnt(0)" ::: "memory"); }
    SCB; BAR;

    // ---- P4: read A(buf1,mh0)+B(buf1,nh0); stage A-h1(tn0); q(0,0)
    read_a4(smA, 16384 + baseA, af);
    read_b2(smB, 16384 + baseB, bf0);
    if (s0) STG(gAs, 1, tn0, smA, 0);
    SCB; BAR; LGKM0; SCB;
    PRIO1; mfma_q(af, bf0, acc, 0, 0); PRIO0;
    SCB; BAR;

    // ---- P5: read B(buf1,nh1); stage B-h0(tn0); q(0,1)
    read_b2(smB, 16384 + baseB + 2048, bf1);
    if (s0) STG(gBs, 0, tn0, smB, 0);
    SCB; BAR; LGKM0; SCB;
    PRIO1; mfma_q(af, bf1, acc, 0, 2); PRIO0;
    SCB; BAR;

    // ---- P6: read A(buf1,mh1); stage B-h1(tn0); q(1,1)
    read_a4(smA, 16384 + baseA + 4096, af);
    if (s0) STG(gBs, 1, tn0, smB, 0);
    SCB; BAR; LGKM0; SCB;
    PRIO1; mfma_q(af, bf1, acc, 4, 2); PRIO0;
    SCB; BAR;

    // ---- P7: stage A-h0(tn1)->buf1 (buf1 reads ended P6); q(1,0); vmcnt
    if (s1) STG(gAs, 0, tn1, smA, 1);
    SCB; BAR; SCB;
    PRIO1; mfma_q(af, bf0, acc, 4, 0); PRIO0;
    SCB;
    if (s1) { asm volatile("s_waitcnt vmcnt(1)" ::: "memory"); }
    else    { asm volatile("s_waitcnt vmcnt(0)" ::: "memory"); }
    SCB; BAR;
  }
#undef STG
#undef BAR
#undef SCB
#undef LGKM0
#undef PRIO1
#undef PRIO0

  // ---- epilogue ----
  const float sw = (float)fmax(meanw[0], 1e-5);
#pragma unroll
  for (int m = 0; m < 8; ++m) {
#pragma unroll
    for (int j = 0; j < 4; ++j) {
      const long row = r0 + wr * 128 + m * 16 + (lane >> 4) * 4 + j;
      const float sa = dsA[row] * sw;
#pragma unroll
      for (int n = 0; n < 4; ++n) {
        const long col = c0 + wcn * 64 + n * 16 + (lane & 15);
        float v = (float)acc[m][n][j] * sa + bias[col];
        if (EPI == 1) {
          float gl = 0.5f * v * (1.0f + erff(v * 0.70710678118654752f));
          outf[row * (long)N + col] = gl;
        } else {
          outf[row * (long)N + col] = v;
        }
      }
    }
  }
}

extern "C" void kernel_launch(void* const* d_in, const int* in_sizes, int n_in,
                              void* d_out, int out_size, void* d_ws, size_t ws_size,
                              hipStream_t stream) {
  const float* x     = (const float*)d_in[0];
  const float* gamma = (const float*)d_in[1];
  const float* beta  = (const float*)d_in[2];
  const float* w1    = (const float*)d_in[3];
  const float* b1    = (const float*)d_in[4];
  const float* w2    = (const float*)d_in[5];
  const float* b2    = (const float*)d_in[6];

  char* ws = (char*)d_ws;
  // meta (<256K): part1@0, part2@16K, means@32K, ds1@64K, ds2@128K
  // [1M)        wq1 16M i8
  // [1M+16M)    wq2 16M i8   (quantized upfront -- own slot)
  // [1M+32M)    aq  32M i8
  // [1M+64M)    hq 128M i8   (dense quantized h)
  // peak 193 MiB (< proven-working 385 MiB).
  // d_out (128M) doubles as f32 GELU staging per M-chunk.
  double* part1 = (double*)(ws + 0);
  double* part2 = (double*)(ws + 16384);
  double* means = (double*)(ws + 32768);
  float* ds1  = (float*)(ws + 65536);
  float* ds2  = (float*)(ws + 131072);
  signed char* wq1 = (signed char*)(ws + 1048576l);
  signed char* wq2 = (signed char*)(ws + 17825792l);
  signed char* aq  = (signed char*)(ws + 34603008l);
  signed char* hq  = (signed char*)(ws + 68157440l);

  const int NW = 16777216;  // elements in each weight matrix
  float* hstage = (float*)d_out;  // 4096 x 8192 f32 = 128 MiB, dead until GEMM2

  absmean_partial2<<<4096, 256, 0, stream>>>(w1, w2, NW, part1, part2);
  absmean_final2<<<2, 256, 0, stream>>>(part1, part2, 2048, (double)NW, means);
  wquant2_kernel<<<32768, 256, 0, stream>>>(w1, w2, means, wq1, wq2, NW);
  ln_quant_kernel<<<16384, 256, 0, stream>>>(x, gamma, beta, aq, ds1);

  // GEMM1 in 4 M-chunks: f32 gelu -> d_out staging, requant -> dense i8 hq
  for (int c = 0; c < 4; ++c) {
    const long r0 = (long)c * MCHUNK;
    gemm256_kernel<1><<<(H_DIM / 256) * (MCHUNK / 256), 512, 0, stream>>>(
        aq + r0 * D_DIM, wq1, ds1 + r0, means + 0, b1, hstage,
        H_DIM / 256, H_DIM, D_DIM);
    hquant32_kernel<<<MCHUNK, 256, 0, stream>>>(
        hstage, hq + r0 * H_DIM, ds2 + r0);
  }

  // GEMM2: out = hq . wq2^T * (ds2*sw2) + b2
  gemm256_kernel<2><<<(D_DIM / 256) * (M_DIM / 256), 512, 0, stream>>>(
      hq, wq2, ds2, means + 1, b2, (float*)d_out,
      D_DIM / 256, D_DIM, H_DIM);
}

// Round 19
// 875.747 us; speedup vs baseline: 1.2648x; 1.1282x over previous
//
#include <hip/hip_runtime.h>
#include <hip/hip_bf16.h>

// BitNet FFN: LN -> act_quant/ternary-W matmul -> GELU(erf) -> act_quant/ternary-W matmul
// Shapes: x[4,4096,2048] f32, w1[8192,2048], w2[2048,8192], out [16384,2048] f32.
// R19: occupancy experiment -- per-wave tile 64x64 (acc 64 i32) so total regs
// fit 128 -> 4 waves/SIMD (launch_bounds(512,4)), block 256x128 (8 waves,
// 4Mx2N), LDS 48KB -> 2 blocks/CU = 16 waves/CU. R5-R14 showed 2 waves/SIMD
// serializes MFMA+LDS pipes; more resident waves let the HW scheduler
// interleave them (m114). Single-queue vmcnt ledger (ALL stages are
// global_load_lds -- the R15-17 mixed-queue failure class is excluded):
// P0: A(t1)->buf1; P1: B(t0+2)->buf0, vmcnt(1); P2: A(t0+2)->buf0;
// P3: B(t1+2)->buf1, vmcnt(1). R10 swizzle + double-barrier phases.
// i8 MFMA 16x16x64; i32 accum exact -> output bit-identical (absmax 2.539e-2).
// Peak ws 193 MiB; d_out doubles as f32 GELU staging per M-chunk.

typedef __attribute__((ext_vector_type(4))) int int4v;

#define D_DIM 2048
#define H_DIM 8192
#define M_DIM 16384
#define MCHUNK 4096

// ---------- small helpers ----------
__device__ __forceinline__ float block_sum(float v, float* buf) {
#pragma unroll
  for (int o = 32; o > 0; o >>= 1) v += __shfl_down(v, o, 64);
  const int lane = threadIdx.x & 63, w = threadIdx.x >> 6;
  if (lane == 0) buf[w] = v;
  __syncthreads();
  float r = buf[0] + buf[1] + buf[2] + buf[3];
  __syncthreads();
  return r;
}
__device__ __forceinline__ float block_max(float v, float* buf) {
#pragma unroll
  for (int o = 32; o > 0; o >>= 1) v = fmaxf(v, __shfl_down(v, o, 64));
  const int lane = threadIdx.x & 63, w = threadIdx.x >> 6;
  if (lane == 0) buf[w] = v;
  __syncthreads();
  float r = fmaxf(fmaxf(buf[0], buf[1]), fmaxf(buf[2], buf[3]));
  __syncthreads();
  return r;
}

__device__ __forceinline__ void lds16(const signed char* g, signed char* l) {
  __builtin_amdgcn_global_load_lds(
      (const __attribute__((address_space(1))) unsigned int*)g,
      (__attribute__((address_space(3))) unsigned int*)l, 16, 0, 0);
}

// ---------- weight abs-mean, both matrices in one dispatch ----------
__global__ __launch_bounds__(256) void absmean_partial2(const float* __restrict__ w1,
                                                        const float* __restrict__ w2,
                                                        int n, double* __restrict__ part1,
                                                        double* __restrict__ part2) {
  __shared__ float buf[4];
  const int half = gridDim.x >> 1;
  const bool second = (int)blockIdx.x >= half;
  const float* w = second ? w2 : w1;
  double* part = second ? part2 : part1;
  const int bid = second ? (blockIdx.x - half) : blockIdx.x;
  float s = 0.0f;
  const long stride = (long)half * 256 * 4;
  for (long i = ((long)bid * 256 + threadIdx.x) * 4; i < n; i += stride) {
    float4 v = *(const float4*)(w + i);
    s += fabsf(v.x) + fabsf(v.y) + fabsf(v.z) + fabsf(v.w);
  }
  float r = block_sum(s, buf);
  if (threadIdx.x == 0) part[bid] = (double)r;
}

__global__ __launch_bounds__(256) void absmean_final2(const double* __restrict__ part1,
                                                      const double* __restrict__ part2,
                                                      int nb, double n,
                                                      double* __restrict__ out) {
  __shared__ double buf[4];
  const double* part = (blockIdx.x == 0) ? part1 : part2;
  double s = 0.0;
  for (int i = threadIdx.x; i < nb; i += 256) s += part[i];
#pragma unroll
  for (int o = 32; o > 0; o >>= 1) s += __shfl_down(s, o, 64);
  const int lane = threadIdx.x & 63, w = threadIdx.x >> 6;
  if (lane == 0) buf[w] = s;
  __syncthreads();
  if (threadIdx.x == 0) out[blockIdx.x] = (buf[0] + buf[1] + buf[2] + buf[3]) / n;
}

// ---------- ternary weight quant -> i8 {-1,0,1}, both matrices ----------
__global__ __launch_bounds__(256) void wquant2_kernel(const float* __restrict__ w1,
                                                      const float* __restrict__ w2,
                                                      const double* __restrict__ means,
                                                      signed char* __restrict__ wq1,
                                                      signed char* __restrict__ wq2, int n) {
  const int half = gridDim.x >> 1;
  const bool second = (int)blockIdx.x >= half;
  const float* w = second ? w2 : w1;
  signed char* wq = second ? wq2 : wq1;
  const double mean = second ? means[1] : means[0];
  const int bid = second ? (blockIdx.x - half) : blockIdx.x;
  long i = ((long)bid * 256 + threadIdx.x) * 4;
  if (i >= n) return;
  const float s = 1.0f / (float)fmax(mean, 1e-5);
  float4 v = *(const float4*)(w + i);
  __align__(4) signed char q[4];
  q[0] = (signed char)(int)fminf(fmaxf(rintf(v.x * s), -1.f), 1.f);
  q[1] = (signed char)(int)fminf(fmaxf(rintf(v.y * s), -1.f), 1.f);
  q[2] = (signed char)(int)fminf(fmaxf(rintf(v.z * s), -1.f), 1.f);
  q[3] = (signed char)(int)fminf(fmaxf(rintf(v.w * s), -1.f), 1.f);
  *(int*)(wq + i) = *(int*)q;
}

// ---------- fused LayerNorm + per-token int8 absmax quant -> i8 ----------
__global__ __launch_bounds__(256) void ln_quant_kernel(const float* __restrict__ x,
                                                       const float* __restrict__ gamma,
                                                       const float* __restrict__ beta,
                                                       signed char* __restrict__ aq,
                                                       float* __restrict__ ds) {
  __shared__ float buf[4];
  const int t = threadIdx.x;
  const long row = blockIdx.x;
  const float* xr = x + row * (long)D_DIM;
  float v[8];
  *(float4*)(v)     = *(const float4*)(xr + t * 8);
  *(float4*)(v + 4) = *(const float4*)(xr + t * 8 + 4);
  float s = 0.f;
#pragma unroll
  for (int i = 0; i < 8; ++i) s += v[i];
  s = block_sum(s, buf);
  const float mu = s * (1.0f / 2048.0f);
  float sq = 0.f;
#pragma unroll
  for (int i = 0; i < 8; ++i) { float d = v[i] - mu; sq += d * d; }
  sq = block_sum(sq, buf);
  const float inv = 1.0f / sqrtf(sq * (1.0f / 2048.0f) + 1e-5f);
  float gam[8], bet[8];
  *(float4*)(gam)     = *(const float4*)(gamma + t * 8);
  *(float4*)(gam + 4) = *(const float4*)(gamma + t * 8 + 4);
  *(float4*)(bet)     = *(const float4*)(beta + t * 8);
  *(float4*)(bet + 4) = *(const float4*)(beta + t * 8 + 4);
  float xn[8]; float am = 0.f;
#pragma unroll
  for (int i = 0; i < 8; ++i) {
    xn[i] = (v[i] - mu) * inv * gam[i] + bet[i];
    am = fmaxf(am, fabsf(xn[i]));
  }
  am = block_max(am, buf);
  am = fmaxf(am, 1e-5f);
  const float qs = 127.0f / am;
  __align__(8) signed char q[8];
#pragma unroll
  for (int i = 0; i < 8; ++i)
    q[i] = (signed char)(int)fminf(fmaxf(rintf(xn[i] * qs), -128.f), 127.f);
  *(long*)(aq + row * D_DIM + t * 8) = *(long*)q;
  if (t == 0) ds[row] = am / 127.0f;
}

// ---------- per-token re-quant from f32 h chunk -> dense i8 ----------
__global__ __launch_bounds__(256) void hquant32_kernel(const float* __restrict__ src,
                                                       signed char* __restrict__ dst,
                                                       float* __restrict__ ds2) {
  __shared__ float buf[4];
  const int t = threadIdx.x;
  const long row = blockIdx.x;
  const float* sr = src + row * (long)H_DIM;
  float v[4][8];
#pragma unroll
  for (int c = 0; c < 4; ++c) {
    *(float4*)(v[c])     = *(const float4*)(sr + (c * 256 + t) * 8);
    *(float4*)(v[c] + 4) = *(const float4*)(sr + (c * 256 + t) * 8 + 4);
  }
  float am = 0.f;
#pragma unroll
  for (int c = 0; c < 4; ++c)
#pragma unroll
    for (int i = 0; i < 8; ++i) am = fmaxf(am, fabsf(v[c][i]));
  am = block_max(am, buf);
  am = fmaxf(am, 1e-5f);
  const float qs = 127.0f / am;
  signed char* dr = dst + row * (long)H_DIM;
#pragma unroll
  for (int c = 0; c < 4; ++c) {
    __align__(8) signed char o[8];
#pragma unroll
    for (int i = 0; i < 8; ++i)
      o[i] = (signed char)(int)fminf(fmaxf(rintf(v[c][i] * qs), -128.f), 127.f);
    *(long*)(dr + (c * 256 + t) * 8) = *(long*)o;
  }
  if (t == 0) ds2[row] = am / 127.0f;
}

// ---------- subtile readers / MFMA (i8, K=64 per instr) ----------
__device__ __forceinline__ void read_a2(const signed char* sm, int base, int4v (&af)[2]) {
#pragma unroll
  for (int ms = 0; ms < 2; ++ms)
    af[ms] = *(const int4v*)&sm[base + ms * 1024];   // 16 rows * 64B
}
__device__ __forceinline__ void read_b4(const signed char* sm, int base, int4v (&bf)[4]) {
#pragma unroll
  for (int ns = 0; ns < 4; ++ns)
    bf[ns] = *(const int4v*)&sm[base + ns * 1024];
}
__device__ __forceinline__ void mfma_half(const int4v (&af)[2], const int4v (&bf)[4],
                                          int4v (&acc)[4][4], int m0) {
#pragma unroll
  for (int ms = 0; ms < 2; ++ms)
#pragma unroll
    for (int ns = 0; ns < 4; ++ns)
      acc[m0 + ms][ns] = __builtin_amdgcn_mfma_i32_16x16x64_i8(
          af[ms], bf[ns], acc[m0 + ms][ns], 0, 0, 0);
}

// ---------- 256x128 BK=64 i8 GEMM, A[M,K] x B[N,K]^T, 64x64 per wave ----------
// 8 waves (4M x 2N), per-wave 64x64 (acc 64 i32 -> ~120 regs total -> 4
// waves/SIMD via launch_bounds(512,4); 2 blocks/CU, 16 waves/CU).
// LDS 48KB: A [dbuf 16384B][half 8192B][row][64B] (256 rows), B [dbuf 8192B]
// [row][64B] (128 rows). R10 chunk-XOR swizzle both sides.
// 4 phases / 2 K-tiles, double-barrier sleep pattern, vmcnt(1) at P1/P3.
// EPI==1: dequant+bias+exact GELU -> f32.  EPI==2: dequant+bias -> f32.
template <int EPI>
__global__ __launch_bounds__(512, 4) void gemm256_kernel(
    const signed char* __restrict__ A,
    const signed char* __restrict__ Bm,
    const float* __restrict__ dsA,
    const double* __restrict__ meanw,
    const float* __restrict__ bias,
    float* __restrict__ outf,
    int NBX, int N, int K) {
  __shared__ __align__(16) signed char smA[2 * 256 * 64];   // 32KB
  __shared__ __align__(16) signed char smB[2 * 128 * 64];   // 16KB
  const int tid = threadIdx.x;
  const int lane = tid & 63;
  const int wid = tid >> 6;
  const int wr = wid >> 1;    // 0..3 (M quarter: 64 rows)
  const int wcn = wid & 1;    // 0..1 (N half: 64 cols)

  // T1: XCD-aware bijective block swizzle (gridDim.x = 1024, %8==0)
  const int cpx = gridDim.x >> 3;
  const int swz = ((int)blockIdx.x & 7) * cpx + ((int)blockIdx.x >> 3);
  const int bx = swz % NBX, by = swz / NBX;
  const long r0 = (long)by * 256;
  const long c0 = (long)bx * 128;

  // staging geometry (R10): thread t -> row t>>2 (0..127), chunk (t&3)^swz(row).
  const int srow = tid >> 2;
  const int schunk = (tid & 3) ^ (srow & 3) ^ ((srow >> 2) & 3);
  const signed char* gAs = A + (r0 + srow) * (long)K + schunk * 16;
  const signed char* gBs = Bm + (c0 + srow) * (long)K + schunk * 16;

  // fragment-read geometry (R10): row base+frow, chunk (lane>>4)^swz(frow).
  const int frow = lane & 15;
  const int fchunk = (lane >> 4) ^ (frow & 3) ^ ((frow >> 2) & 3);
  const int fbyte = frow * 64 + fchunk * 16;
  // A: wave wr rows wr*64..+63 -> half wr>>1, sub-base (wr&1)*4096
  const int baseA = (wr >> 1) * 8192 + (wr & 1) * 4096 + fbyte;  // + d*16384 (+ms*1024)
  const int baseB = wcn * 4096 + fbyte;                          // + d*8192  (+ns*1024)

  int4v acc[4][4] = {};
  int4v af[2], bf[4];
  const int nk = K >> 6;            // BK = 64 K-tiles
  const int nk2 = nk >> 1;

// stage A half h (128 rows) of K-tile t into dbuf d (1 load/thread)
#define STGA(h, t, d)                                                         \
    lds16(gAs + (long)((h) * 128) * K + (long)(t) * 64,                       \
          &smA[(d) * 16384 + (h) * 8192 + tid * 16]);
// stage B tile (128 rows) of K-tile t into dbuf d (1 load/thread)
#define STGB(t, d)                                                            \
    lds16(gBs + (long)(t) * 64, &smB[(d) * 8192 + tid * 16]);
#define BAR  __builtin_amdgcn_s_barrier()
#define SCB  __builtin_amdgcn_sched_barrier(0)
#define LGKM0 asm volatile("s_waitcnt lgkmcnt(0)" ::: "memory")
#define PRIO1 __builtin_amdgcn_s_setprio(1)
#define PRIO0 __builtin_amdgcn_s_setprio(0)

  // prologue: A(t0)->buf0 (2 loads), B(t0)->buf0, B(t1)->buf1.
  // vmcnt(1) drains first 3 (buf0 complete), leaves B(t1) in flight.
  STGA(0, 0, 0); STGA(1, 0, 0); STGB(0, 0);
  STGB(1, 1);
  asm volatile("s_waitcnt vmcnt(1)" ::: "memory");
  SCB; BAR; SCB;

  for (int i = 0; i < nk2; ++i) {
    const int t0 = 2 * i, t1 = 2 * i + 1;
    const bool s = (i < nk2 - 1);

    // ---- P0: read A-lo(buf0)+B(buf0); stage A(t1)->buf1 (h0,h1); MFMA m0-1
    read_a2(smA, baseA, af);
    read_b4(smB, baseB, bf);
    STGA(0, t1, 1); STGA(1, t1, 1);
    SCB; BAR; LGKM0; SCB;
    PRIO1; mfma_half(af, bf, acc, 0); PRIO0;
    SCB; BAR;

    // ---- P1: read A-hi(buf0); stage B(t0+2)->buf0; MFMA m2-3; vmcnt(1)
    read_a2(smA, baseA + 2048, af);
    if (s) STGB(t0 + 2, 0);
    SCB; BAR; LGKM0; SCB;
    PRIO1; mfma_half(af, bf, acc, 2); PRIO0;
    SCB;
    if (s) { asm volatile("s_waitcnt vmcnt(1)" ::: "memory"); }   // B(t1),A(t1) landed
    else   { asm volatile("s_waitcnt vmcnt(0)" ::: "memory"); }
    SCB; BAR;

    // ---- P2: read A-lo(buf1)+B(buf1); stage A(t0+2)->buf0 (h0,h1); MFMA m0-1
    read_a2(smA, 16384 + baseA, af);
    read_b4(smB, 8192 + baseB, bf);
    if (s) { STGA(0, t0 + 2, 0); STGA(1, t0 + 2, 0); }
    SCB; BAR; LGKM0; SCB;
    PRIO1; mfma_half(af, bf, acc, 0); PRIO0;
    SCB; BAR;

    // ---- P3: read A-hi(buf1); stage B(t1+2)->buf1; MFMA m2-3; vmcnt(1)
    read_a2(smA, 16384 + baseA + 2048, af);
    if (s) STGB(t1 + 2, 1);
    SCB; BAR; LGKM0; SCB;
    PRIO1; mfma_half(af, bf, acc, 2); PRIO0;
    SCB;
    if (s) { asm volatile("s_waitcnt vmcnt(1)" ::: "memory"); }   // B(t0+2),A(t0+2) landed
    else   { asm volatile("s_waitcnt vmcnt(0)" ::: "memory"); }
    SCB; BAR;
  }
#undef STGA
#undef STGB
#undef BAR
#undef SCB
#undef LGKM0
#undef PRIO1
#undef PRIO0

  // ---- epilogue ----
  const float sw = (float)fmax(meanw[0], 1e-5);
#pragma unroll
  for (int m = 0; m < 4; ++m) {
#pragma unroll
    for (int j = 0; j < 4; ++j) {
      const long row = r0 + wr * 64 + m * 16 + (lane >> 4) * 4 + j;
      const float sa = dsA[row] * sw;
#pragma unroll
      for (int n = 0; n < 4; ++n) {
        const long col = c0 + wcn * 64 + n * 16 + (lane & 15);
        float v = (float)acc[m][n][j] * sa + bias[col];
        if (EPI == 1) {
          float gl = 0.5f * v * (1.0f + erff(v * 0.70710678118654752f));
          outf[row * (long)N + col] = gl;
        } else {
          outf[row * (long)N + col] = v;
        }
      }
    }
  }
}

extern "C" void kernel_launch(void* const* d_in, const int* in_sizes, int n_in,
                              void* d_out, int out_size, void* d_ws, size_t ws_size,
                              hipStream_t stream) {
  const float* x     = (const float*)d_in[0];
  const float* gamma = (const float*)d_in[1];
  const float* beta  = (const float*)d_in[2];
  const float* w1    = (const float*)d_in[3];
  const float* b1    = (const float*)d_in[4];
  const float* w2    = (const float*)d_in[5];
  const float* b2    = (const float*)d_in[6];

  char* ws = (char*)d_ws;
  // meta (<256K): part1@0, part2@16K, means@32K, ds1@64K, ds2@128K
  // [1M)        wq1 16M i8
  // [1M+16M)    wq2 16M i8
  // [1M+32M)    aq  32M i8
  // [1M+64M)    hq 128M i8
  // peak 193 MiB.  d_out (128M) doubles as f32 GELU staging per M-chunk.
  double* part1 = (double*)(ws + 0);
  double* part2 = (double*)(ws + 16384);
  double* means = (double*)(ws + 32768);
  float* ds1  = (float*)(ws + 65536);
  float* ds2  = (float*)(ws + 131072);
  signed char* wq1 = (signed char*)(ws + 1048576l);
  signed char* wq2 = (signed char*)(ws + 17825792l);
  signed char* aq  = (signed char*)(ws + 34603008l);
  signed char* hq  = (signed char*)(ws + 68157440l);

  const int NW = 16777216;  // elements in each weight matrix
  float* hstage = (float*)d_out;  // 4096 x 8192 f32 = 128 MiB, dead until GEMM2

  absmean_partial2<<<4096, 256, 0, stream>>>(w1, w2, NW, part1, part2);
  absmean_final2<<<2, 256, 0, stream>>>(part1, part2, 2048, (double)NW, means);
  wquant2_kernel<<<32768, 256, 0, stream>>>(w1, w2, means, wq1, wq2, NW);
  ln_quant_kernel<<<16384, 256, 0, stream>>>(x, gamma, beta, aq, ds1);

  // GEMM1 in 4 M-chunks: f32 gelu -> d_out staging, requant -> dense i8 hq
  for (int c = 0; c < 4; ++c) {
    const long r0 = (long)c * MCHUNK;
    gemm256_kernel<1><<<(H_DIM / 128) * (MCHUNK / 256), 512, 0, stream>>>(
        aq + r0 * D_DIM, wq1, ds1 + r0, means + 0, b1, hstage,
        H_DIM / 128, H_DIM, D_DIM);
    hquant32_kernel<<<MCHUNK, 256, 0, stream>>>(
        hstage, hq + r0 * H_DIM, ds2 + r0);
  }

  // GEMM2: out = hq . wq2^T * (ds2*sw2) + b2
  gemm256_kernel<2><<<(D_DIM / 128) * (M_DIM / 256), 512, 0, stream>>>(
      hq, wq2, ds2, means + 1, b2, (float*)d_out,
      D_DIM / 128, D_DIM, H_DIM);
}